// Round 1
// baseline (25.354 us; speedup 1.0000x reference)
//
#include <hip/hip_runtime.h>
#include <math.h>

#define TLEN  256
#define NFEAT 16
#define NBATCH 32
#define BETA  2.5f
#define EPSW  1e-12f
#define W_BI  0.05f
#define W_L2  0.01f

__device__ inline float sigm(float v) { return 1.f / (1.f + __expf(-v)); }

__device__ inline float wredmax(float v) {
#pragma unroll
    for (int o = 32; o; o >>= 1) v = fmaxf(v, __shfl_xor(v, o));
    return v;
}
__device__ inline float wredmin(float v) {
#pragma unroll
    for (int o = 32; o; o >>= 1) v = fminf(v, __shfl_xor(v, o));
    return v;
}
__device__ inline float wredsum(float v) {
#pragma unroll
    for (int o = 32; o; o >>= 1) v += __shfl_xor(v, o);
    return v;
}

// One block per (batch, feature). 256 threads, thread = window index i.
__global__ __launch_bounds__(TLEN) void stage12_kernel(
    const float* __restrict__ x, const float* __restrict__ t1,
    const float* __restrict__ t2, const float* __restrict__ a,
    const float* __restrict__ b, const float* __restrict__ tvt,
    float* __restrict__ r1_out)
{
    const int blk = blockIdx.x;
    const int bb  = blk >> 4;    // batch
    const int f   = blk & 15;    // feature
    const int tid = threadIdx.x;

    __shared__ float rs[TLEN];   // r1p row
    __shared__ float lw[TLEN];   // log(w1 + eps)
    __shared__ float redA[4], redB[4], redC[4], redD[4];

    // r1p[t] = a[f]*x[bb,t,0] - b[f]
    const float v0 = a[f] * x[(bb * TLEN + tid) * 2] - b[f];
    rs[tid] = v0;

    // window-1 params (row 0 of t1/t2), clipped per reference
    {
        float t2h = fminf(fmaxf(t2[f], 0.f), (float)(TLEN - 1));
        float t1h = fminf(fmaxf(t1[f], 0.f), (float)(TLEN - 1));
        t1h = (t1h >= t2h - 1.f) ? (t2h - 1.f) : t1h;
        const float jj = (float)tid;
        const float w1 = sigm(BETA * (jj - t1h)) * sigm(BETA * (t2h - jj));
        lw[tid] = __logf(w1 + EPSW);
    }
    __syncthreads();

    // block max/min of rs -> softmax shift constants (shift-invariant)
    {
        float wm = wredmax(v0), wn = wredmin(v0);
        if ((tid & 63) == 0) { redA[tid >> 6] = wm; redB[tid >> 6] = wn; }
    }
    __syncthreads();
    const float vmax = fmaxf(fmaxf(redA[0], redA[1]), fmaxf(redA[2], redA[3]));
    const float vmin = fminf(fminf(redB[0], redB[1]), fminf(redB[2], redB[3]));
    const float Mp =  BETA * vmax;   // shift for +beta*v logits
    const float Mm = -BETA * vmin;   // shift for -beta*v logits

    // stage 1: weighted soft max & min over the window for this i = tid
    float sp = 0.f, np = 0.f, sm = 0.f, nm = 0.f;
#pragma unroll 4
    for (int j = 0; j < TLEN; ++j) {
        int t = tid + j; t = (t > TLEN - 1) ? (TLEN - 1) : t;
        const float vv = rs[t];
        const float l  = lw[j];
        const float ep = __expf(fmaf(BETA, vv, l) - Mp);
        sp += ep; np = fmaf(ep, vv, np);
        const float em = __expf(fmaf(-BETA, vv, l) - Mm);
        sm += em; nm = fmaf(em, vv, nm);
    }
    const float F1 = np / sp;
    const float G1 = nm / sm;
    const float tv0 = fminf(fmaxf(tvt[f], 0.f), 1.f);
    const float y = tv0 * F1 + (1.f - tv0) * G1;   // r1i[bb,f,tid]

    // window-2 log-weights for i = tid (row 1 of t1/t2)
    float lw2;
    {
        float t2h = fminf(fmaxf(t2[NFEAT + f], 0.f), (float)(TLEN - 1));
        float t1h = fminf(fmaxf(t1[NFEAT + f], 0.f), (float)(TLEN - 1));
        t1h = (t1h >= t2h - 1.f) ? (t2h - 1.f) : t1h;
        const float jj = (float)tid;
        const float w2 = sigm(BETA * (jj - t1h)) * sigm(BETA * (t2h - jj));
        lw2 = __logf(w2 + EPSW);
    }

    // stage 2: block-wide weighted soft max/min over i of y
    __syncthreads();              // protect redA/redB reuse
    {
        float ym = wredmax(y), yn = wredmin(y);
        if ((tid & 63) == 0) { redA[tid >> 6] = ym; redB[tid >> 6] = yn; }
    }
    __syncthreads();
    const float ymax = fmaxf(fmaxf(redA[0], redA[1]), fmaxf(redA[2], redA[3]));
    const float ymin = fminf(fminf(redB[0], redB[1]), fminf(redB[2], redB[3]));

    const float ep2 = __expf(fmaf(BETA, y, lw2) - BETA * ymax);
    const float em2 = __expf(fmaf(-BETA, y, lw2) + BETA * ymin);
    float sp2 = wredsum(ep2);
    float np2 = wredsum(ep2 * y);
    float sm2 = wredsum(em2);
    float nm2 = wredsum(em2 * y);
    __syncthreads();              // protect red arrays reuse
    if ((tid & 63) == 0) {
        redA[tid >> 6] = sp2; redB[tid >> 6] = np2;
        redC[tid >> 6] = sm2; redD[tid >> 6] = nm2;
    }
    __syncthreads();
    if (tid == 0) {
        const float SP = redA[0] + redA[1] + redA[2] + redA[3];
        const float NP = redB[0] + redB[1] + redB[2] + redB[3];
        const float SM = redC[0] + redC[1] + redC[2] + redC[3];
        const float NM = redD[0] + redD[1] + redD[2] + redD[3];
        const float F2 = NP / SP, G2 = NM / SM;
        const float tv1 = fminf(fmaxf(tvt[NFEAT + f], 0.f), 1.f);
        r1_out[bb * NFEAT + f] = tv1 * F2 + (1.f - tv1) * G2;
    }
}

// One small block: stage-3 logical soft max/min over features + penalty scalar.
__global__ __launch_bounds__(64) void stage3_kernel(
    const float* __restrict__ r1, const float* __restrict__ p,
    const float* __restrict__ tvt, const float* __restrict__ tvl_in,
    float* __restrict__ out)
{
    const int tid = threadIdx.x;
    const float tvl = fminf(fmaxf(tvl_in[0], 0.f), 1.f);

    if (tid < NBATCH) {
        float vv[NFEAT], lwp[NFEAT];
        float mp = -1e30f, mm = -1e30f;
#pragma unroll
        for (int ff = 0; ff < NFEAT; ++ff) {
            const float pc = fminf(fmaxf(p[ff], 0.f), 1.f);
            const float lwf = __logf(pc + EPSW);
            const float v = r1[tid * NFEAT + ff];
            vv[ff] = v; lwp[ff] = lwf;
            mp = fmaxf(mp, fmaf(BETA, v, lwf));
            mm = fmaxf(mm, fmaf(-BETA, v, lwf));
        }
        float sp = 0.f, np = 0.f, sm = 0.f, nm = 0.f;
#pragma unroll
        for (int ff = 0; ff < NFEAT; ++ff) {
            const float ep = __expf(fmaf(BETA, vv[ff], lwp[ff]) - mp);
            sp += ep; np = fmaf(ep, vv[ff], np);
            const float em = __expf(fmaf(-BETA, vv[ff], lwp[ff]) - mm);
            sm += em; nm = fmaf(em, vv[ff], nm);
        }
        out[tid] = tvl * (np / sp) + (1.f - tvl) * (nm / sm);
    }

    if (tid == 0) {
        float bi = 0.f, l2 = 0.f;
#pragma unroll
        for (int k = 0; k < 2 * NFEAT; ++k) {
            const float t = fminf(fmaxf(tvt[k], 0.f), 1.f);
            bi += t * (1.f - t);
        }
        bi += tvl * (1.f - tvl);
#pragma unroll
        for (int ff = 0; ff < NFEAT; ++ff) {
            const float pc = fminf(fmaxf(p[ff], 0.f), 1.f);
            bi += pc * (1.f - pc);
            l2 = fmaf(pc, pc, l2);
        }
        out[NBATCH] = W_BI * bi + W_L2 * l2;
    }
}

extern "C" void kernel_launch(void* const* d_in, const int* in_sizes, int n_in,
                              void* d_out, int out_size, void* d_ws, size_t ws_size,
                              hipStream_t stream)
{
    const float* x   = (const float*)d_in[0];
    const float* t1  = (const float*)d_in[1];
    const float* t2  = (const float*)d_in[2];
    const float* a   = (const float*)d_in[3];
    const float* b   = (const float*)d_in[4];
    const float* p   = (const float*)d_in[5];
    const float* tvt = (const float*)d_in[6];
    const float* tvl = (const float*)d_in[7];
    float* out = (float*)d_out;
    float* r1  = (float*)d_ws;   // NBATCH*NFEAT floats scratch

    stage12_kernel<<<NBATCH * NFEAT, TLEN, 0, stream>>>(x, t1, t2, a, b, tvt, r1);
    stage3_kernel<<<1, 64, 0, stream>>>(r1, p, tvt, tvl, out);
}

// Round 2
// 19.606 us; speedup vs baseline: 1.2932x; 1.2932x over previous
//
#include <hip/hip_runtime.h>
#include <math.h>

#define TLEN   256
#define NFEAT  16
#define NBATCH 32
#define BETA   2.5f
#define EPSW   1e-12f
#define W_BI   0.05f
#define W_L2   0.01f
#define L2E    1.4426950408889634f
#define LB     (BETA * L2E)

#if __has_builtin(__builtin_amdgcn_exp2f)
#define EXP2(x) __builtin_amdgcn_exp2f(x)
#else
#define EXP2(x) exp2f(x)
#endif

__device__ inline float sigm(float v) { return 1.f / (1.f + __expf(-v)); }

__device__ inline float wredmax(float v) {
#pragma unroll
    for (int o = 32; o; o >>= 1) v = fmaxf(v, __shfl_xor(v, o));
    return v;
}
__device__ inline float wredmin(float v) {
#pragma unroll
    for (int o = 32; o; o >>= 1) v = fminf(v, __shfl_xor(v, o));
    return v;
}
__device__ inline float wredsum(float v) {
#pragma unroll
    for (int o = 32; o; o >>= 1) v += __shfl_xor(v, o);
    return v;
}

// One block per (batch, feature): 1024 threads = 256 window-starts (i) x 4 j-quarters (q).
__global__ __launch_bounds__(1024, 8) void stage12_kernel(
    const float* __restrict__ x, const float* __restrict__ t1,
    const float* __restrict__ t2, const float* __restrict__ a,
    const float* __restrict__ b, const float* __restrict__ tvt,
    float* __restrict__ r1_out)
{
    const int bf  = blockIdx.x;
    const int bb  = bf >> 4;
    const int f   = bf & 15;
    const int tid = threadIdx.x;
    const int i   = tid & 255;
    const int q   = tid >> 8;     // 0..3
    const int wave = tid >> 6;    // 0..15

    __shared__ float  bl_pad[512];   // LB * v[min(t,255)]
    __shared__ float  lw_raw[256];
    __shared__ float2 lwpm[256];     // (L2E*(lw - beta*vmax), L2E*lw + LB*vmin)
    __shared__ float  part[4][1024]; // sp, np, sm, nm partials
    __shared__ float  redA[4], redB[4];

    // ---- setup: signal + raw log-weights ----
    float v = 0.f;
    if (tid < 512) {
        const int t = (tid < 255) ? tid : 255;
        v = a[f] * x[(bb * TLEN + t) * 2] - b[f];
        bl_pad[tid] = LB * v;
    }
    if (tid < 256) {
        float t2h = fminf(fmaxf(t2[f], 0.f), (float)(TLEN - 1));
        float t1h = fminf(fmaxf(t1[f], 0.f), (float)(TLEN - 1));
        t1h = (t1h >= t2h - 1.f) ? (t2h - 1.f) : t1h;
        const float jj = (float)tid;
        const float w1 = sigm(BETA * (jj - t1h)) * sigm(BETA * (t2h - jj));
        lw_raw[tid] = __logf(w1 + EPSW);
    }
    if (wave < 4) {   // threads 0..255 hold valid v
        const float wm = wredmax(v), wn = wredmin(v);
        if ((tid & 63) == 0) { redA[wave] = wm; redB[wave] = wn; }
    }
    __syncthreads();  // S1

    const float vmax = fmaxf(fmaxf(redA[0], redA[1]), fmaxf(redA[2], redA[3]));
    const float vmin = fminf(fminf(redB[0], redB[1]), fminf(redB[2], redB[3]));
    if (tid < 256) {
        const float lw = lw_raw[tid];
        lwpm[tid] = make_float2(L2E * (lw - BETA * vmax), fmaf(LB, vmin, L2E * lw));
    }
    __syncthreads();  // S2

    // ---- stage 1: this thread handles window-start i, j in [64q, 64q+64) ----
    float sp = 0.f, np = 0.f, sm = 0.f, nm = 0.f;
    {
        const float*  blp = &bl_pad[i + q * 64];
        const float2* lwp = &lwpm[q * 64];
#pragma unroll 4
        for (int j = 0; j < 64; ++j) {
            const float  blv = blp[j];
            const float2 l2v = lwp[j];
            const float ep = EXP2(blv + l2v.x);
            const float em = EXP2(l2v.y - blv);
            sp += ep; np = fmaf(ep, blv, np);
            sm += em; nm = fmaf(em, blv, nm);
        }
    }
    part[0][tid] = sp; part[1][tid] = np; part[2][tid] = sm; part[3][tid] = nm;
    __syncthreads();  // S3

    // ---- combine partials, stage-2 value y per i ----
    float y = 0.f, lw2 = 0.f;
    if (tid < 256) {
        const float SP = part[0][tid] + part[0][tid + 256] + part[0][tid + 512] + part[0][tid + 768];
        const float NP = part[1][tid] + part[1][tid + 256] + part[1][tid + 512] + part[1][tid + 768];
        const float SM = part[2][tid] + part[2][tid + 256] + part[2][tid + 512] + part[2][tid + 768];
        const float NM = part[3][tid] + part[3][tid + 256] + part[3][tid + 512] + part[3][tid + 768];
        const float F1 = NP / (SP * LB);
        const float G1 = NM / (SM * LB);
        const float tv0 = fminf(fmaxf(tvt[f], 0.f), 1.f);
        y = tv0 * F1 + (1.f - tv0) * G1;

        float t2h = fminf(fmaxf(t2[NFEAT + f], 0.f), (float)(TLEN - 1));
        float t1h = fminf(fmaxf(t1[NFEAT + f], 0.f), (float)(TLEN - 1));
        t1h = (t1h >= t2h - 1.f) ? (t2h - 1.f) : t1h;
        const float jj = (float)tid;
        const float w2 = sigm(BETA * (jj - t1h)) * sigm(BETA * (t2h - jj));
        lw2 = __logf(w2 + EPSW);
    }
    __syncthreads();  // S4 (part reads done; redA/redB free)

    if (wave < 4) {
        const float ym = wredmax(y), yn = wredmin(y);
        if ((tid & 63) == 0) { redA[wave] = ym; redB[wave] = yn; }
    }
    __syncthreads();  // S5

    const float ymax = fmaxf(fmaxf(redA[0], redA[1]), fmaxf(redA[2], redA[3]));
    const float ymin = fminf(fminf(redB[0], redB[1]), fminf(redB[2], redB[3]));

    float c0 = 0.f, c1 = 0.f, c2 = 0.f, c3 = 0.f;
    if (tid < 256) {
        const float ep2 = EXP2(fmaf(LB, y - ymax, L2E * lw2));
        const float em2 = EXP2(fmaf(LB, ymin - y, L2E * lw2));
        c0 = ep2; c1 = ep2 * y; c2 = em2; c3 = em2 * y;
    }
    if (wave < 4) {
        c0 = wredsum(c0); c1 = wredsum(c1); c2 = wredsum(c2); c3 = wredsum(c3);
        if ((tid & 63) == 0) { part[0][wave] = c0; part[1][wave] = c1; part[2][wave] = c2; part[3][wave] = c3; }
    }
    __syncthreads();  // S6

    if (tid == 0) {
        const float SP2 = part[0][0] + part[0][1] + part[0][2] + part[0][3];
        const float NP2 = part[1][0] + part[1][1] + part[1][2] + part[1][3];
        const float SM2 = part[2][0] + part[2][1] + part[2][2] + part[2][3];
        const float NM2 = part[3][0] + part[3][1] + part[3][2] + part[3][3];
        const float F2 = NP2 / SP2, G2 = NM2 / SM2;
        const float tv1 = fminf(fmaxf(tvt[NFEAT + f], 0.f), 1.f);
        r1_out[bb * NFEAT + f] = tv1 * F2 + (1.f - tv1) * G2;
    }
}

// One small block: stage-3 logical soft max/min over features + penalty scalar.
__global__ __launch_bounds__(64) void stage3_kernel(
    const float* __restrict__ r1, const float* __restrict__ p,
    const float* __restrict__ tvt, const float* __restrict__ tvl_in,
    float* __restrict__ out)
{
    const int tid = threadIdx.x;
    const float tvl = fminf(fmaxf(tvl_in[0], 0.f), 1.f);

    if (tid < NBATCH) {
        float vv[NFEAT], lwp[NFEAT];
        float mp = -1e30f, mm = -1e30f;
#pragma unroll
        for (int ff = 0; ff < NFEAT; ++ff) {
            const float pc = fminf(fmaxf(p[ff], 0.f), 1.f);
            const float lwf = __logf(pc + EPSW);
            const float v = r1[tid * NFEAT + ff];
            vv[ff] = v; lwp[ff] = lwf;
            mp = fmaxf(mp, fmaf(BETA, v, lwf));
            mm = fmaxf(mm, fmaf(-BETA, v, lwf));
        }
        float sp = 0.f, np = 0.f, sm = 0.f, nm = 0.f;
#pragma unroll
        for (int ff = 0; ff < NFEAT; ++ff) {
            const float ep = __expf(fmaf(BETA, vv[ff], lwp[ff]) - mp);
            sp += ep; np = fmaf(ep, vv[ff], np);
            const float em = __expf(fmaf(-BETA, vv[ff], lwp[ff]) - mm);
            sm += em; nm = fmaf(em, vv[ff], nm);
        }
        out[tid] = tvl * (np / sp) + (1.f - tvl) * (nm / sm);
    }

    if (tid == 0) {
        float bi = 0.f, l2 = 0.f;
#pragma unroll
        for (int k = 0; k < 2 * NFEAT; ++k) {
            const float t = fminf(fmaxf(tvt[k], 0.f), 1.f);
            bi += t * (1.f - t);
        }
        bi += tvl * (1.f - tvl);
#pragma unroll
        for (int ff = 0; ff < NFEAT; ++ff) {
            const float pc = fminf(fmaxf(p[ff], 0.f), 1.f);
            bi += pc * (1.f - pc);
            l2 = fmaf(pc, pc, l2);
        }
        out[NBATCH] = W_BI * bi + W_L2 * l2;
    }
}

extern "C" void kernel_launch(void* const* d_in, const int* in_sizes, int n_in,
                              void* d_out, int out_size, void* d_ws, size_t ws_size,
                              hipStream_t stream)
{
    const float* x   = (const float*)d_in[0];
    const float* t1  = (const float*)d_in[1];
    const float* t2  = (const float*)d_in[2];
    const float* a   = (const float*)d_in[3];
    const float* b   = (const float*)d_in[4];
    const float* p   = (const float*)d_in[5];
    const float* tvt = (const float*)d_in[6];
    const float* tvl = (const float*)d_in[7];
    float* out = (float*)d_out;
    float* r1  = (float*)d_ws;   // NBATCH*NFEAT floats scratch

    stage12_kernel<<<NBATCH * NFEAT, 1024, 0, stream>>>(x, t1, t2, a, b, tvt, r1);
    stage3_kernel<<<1, 64, 0, stream>>>(r1, p, tvt, tvl, out);
}

// Round 3
// 16.594 us; speedup vs baseline: 1.5279x; 1.1815x over previous
//
#include <hip/hip_runtime.h>
#include <math.h>

#define TLEN   256
#define NFEAT  16
#define NBATCH 32
#define BETA   2.5f
#define EPSW   1e-12f
#define W_BI   0.05f
#define W_L2   0.01f
#define L2E    1.4426950408889634f
#define LB     (BETA * L2E)
#define SLACK  16

#if __has_builtin(__builtin_amdgcn_exp2f)
#define EXP2(x) __builtin_amdgcn_exp2f(x)
#else
#define EXP2(x) exp2f(x)
#endif

__device__ inline float sigm(float v) { return 1.f / (1.f + __expf(-v)); }

__device__ inline float wredmax(float v) {
#pragma unroll
    for (int o = 32; o; o >>= 1) v = fmaxf(v, __shfl_xor(v, o));
    return v;
}
__device__ inline float wredmin(float v) {
#pragma unroll
    for (int o = 32; o; o >>= 1) v = fminf(v, __shfl_xor(v, o));
    return v;
}
__device__ inline float wredsum(float v) {
#pragma unroll
    for (int o = 32; o; o >>= 1) v += __shfl_xor(v, o);
    return v;
}

// One block per (batch, feature): 256 threads; thread index serves as t / j / i.
__global__ __launch_bounds__(256) void stage12_kernel(
    const float* __restrict__ x, const float* __restrict__ t1,
    const float* __restrict__ t2, const float* __restrict__ a,
    const float* __restrict__ b, const float* __restrict__ tvt,
    float* __restrict__ r1_out)
{
    const int bf   = blockIdx.x;
    const int bb   = bf >> 4;
    const int f    = bf & 15;
    const int tid  = threadIdx.x;
    const int wave = tid >> 6;
    const int lane = tid & 63;

    __shared__ float4 PQ[512];      // (E, E*blv, Em, Em*blv); [256..511] = 0 pad
    __shared__ float  wpe[256];     // w1 + eps
    __shared__ float  Wsuf[257];    // suffix sums of wpe
    __shared__ float  wtot[4];
    __shared__ float  redA[4], redB[4], redC[4], redD[4];

    // ---- window-1 params (uniform across block) ----
    float t1h, t2h;
    {
        t2h = fminf(fmaxf(t2[f], 0.f), (float)(TLEN - 1));
        t1h = fminf(fmaxf(t1[f], 0.f), (float)(TLEN - 1));
        t1h = (t1h >= t2h - 1.f) ? (t2h - 1.f) : t1h;
    }

    // ---- signal value for this t = tid ----
    const float v   = a[f] * x[(bb * TLEN + tid) * 2] - b[f];
    const float blv = LB * v;

    // wave max/min of v
    {
        const float wm = wredmax(v), wn = wredmin(v);
        if (lane == 0) { redA[wave] = wm; redB[wave] = wn; }
    }

    // ---- w1 + eps for j = tid, and wave-level suffix scan ----
    const float jj = (float)tid;
    const float w1 = sigm(BETA * (jj - t1h)) * sigm(BETA * (t2h - jj));
    const float wp = w1 + EPSW;
    wpe[tid] = wp;
    float s = wp;
#pragma unroll
    for (int off = 1; off < 64; off <<= 1) {
        const float o = __shfl_down(s, off);
        s += (lane + off < 64) ? o : 0.f;
    }
    if (lane == 0) wtot[wave] = s;
    __syncthreads();  // S1

    const float vmax = fmaxf(fmaxf(redA[0], redA[1]), fmaxf(redA[2], redA[3]));
    const float vmin = fminf(fminf(redB[0], redB[1]), fminf(redB[2], redB[3]));

    // finish global suffix sums
    {
        float add = 0.f;
#pragma unroll
        for (int w = 1; w < 4; ++w) if (wave + w < 4) add += wtot[wave + w];
        Wsuf[tid] = s + add;
        if (tid == 0) Wsuf[256] = 0.f;
    }

    // exponentials (global shift => E, Em in (0,1])
    const float Ep = EXP2(blv - LB * vmax);
    const float Em = EXP2(LB * vmin - blv);
    PQ[tid]       = make_float4(Ep, Ep * blv, Em, Em * blv);
    PQ[256 + tid] = make_float4(0.f, 0.f, 0.f, 0.f);
    __syncthreads();  // S2

    // ---- stage 1: correlation over supported j, per output i = tid ----
    const int i    = tid;
    const int ib   = tid & ~63;                         // wave's i base
    const int jbeg = max(0, (int)t1h - SLACK);
    const int jend = min(min(TLEN - 1, (int)t2h + SLACK + 1), (TLEN - 1) - ib);

    float sp = 0.f, np = 0.f, sm = 0.f, nm = 0.f;
#pragma unroll 4
    for (int j = jbeg; j <= jend; ++j) {
        const float  wj = wpe[j];
        const float4 pq = PQ[i + j];
        sp = fmaf(wj, pq.x, sp); np = fmaf(wj, pq.y, np);
        sm = fmaf(wj, pq.z, sm); nm = fmaf(wj, pq.w, nm);
    }
    // clamp-region tail: all j >= 256-i use t=255, exact via suffix sums
    {
        const float  Ws = Wsuf[256 - i];
        const float4 pq = PQ[255];
        sp = fmaf(Ws, pq.x, sp); np = fmaf(Ws, pq.y, np);
        sm = fmaf(Ws, pq.z, sm); nm = fmaf(Ws, pq.w, nm);
    }

    const float F1  = np / sp;            // in blv units
    const float G1  = nm / sm;
    const float tv0 = fminf(fmaxf(tvt[f], 0.f), 1.f);
    const float y   = (tv0 * F1 + (1.f - tv0) * G1) * (1.f / LB);  // back to v units

    // ---- stage-2 weights for i = tid ----
    float lw2;
    {
        float t2h2 = fminf(fmaxf(t2[NFEAT + f], 0.f), (float)(TLEN - 1));
        float t1h2 = fminf(fmaxf(t1[NFEAT + f], 0.f), (float)(TLEN - 1));
        t1h2 = (t1h2 >= t2h2 - 1.f) ? (t2h2 - 1.f) : t1h2;
        const float w2 = sigm(BETA * (jj - t1h2)) * sigm(BETA * (t2h2 - jj));
        lw2 = __logf(w2 + EPSW);
    }

    // ---- stage 2: weighted soft max/min over i ----
    {
        const float ym = wredmax(y), yn = wredmin(y);
        if (lane == 0) { redA[wave] = ym; redB[wave] = yn; }
    }
    __syncthreads();  // S3
    const float ymax = fmaxf(fmaxf(redA[0], redA[1]), fmaxf(redA[2], redA[3]));
    const float ymin = fminf(fminf(redB[0], redB[1]), fminf(redB[2], redB[3]));

    const float ep2 = EXP2(fmaf(LB, y - ymax, L2E * lw2));
    const float em2 = EXP2(fmaf(LB, ymin - y, L2E * lw2));
    float c0 = wredsum(ep2);
    float c1 = wredsum(ep2 * y);
    float c2 = wredsum(em2);
    float c3 = wredsum(em2 * y);
    __syncthreads();  // S4 (everyone done reading redA/redB)
    if (lane == 0) { redA[wave] = c0; redB[wave] = c1; redC[wave] = c2; redD[wave] = c3; }
    __syncthreads();  // S5
    if (tid == 0) {
        const float SP2 = redA[0] + redA[1] + redA[2] + redA[3];
        const float NP2 = redB[0] + redB[1] + redB[2] + redB[3];
        const float SM2 = redC[0] + redC[1] + redC[2] + redC[3];
        const float NM2 = redD[0] + redD[1] + redD[2] + redD[3];
        const float F2 = NP2 / SP2, G2 = NM2 / SM2;
        const float tv1 = fminf(fmaxf(tvt[NFEAT + f], 0.f), 1.f);
        r1_out[bb * NFEAT + f] = tv1 * F2 + (1.f - tv1) * G2;
    }
}

// One small block: stage-3 logical soft max/min over features + penalty scalar.
__global__ __launch_bounds__(64) void stage3_kernel(
    const float* __restrict__ r1, const float* __restrict__ p,
    const float* __restrict__ tvt, const float* __restrict__ tvl_in,
    float* __restrict__ out)
{
    const int tid = threadIdx.x;
    const float tvl = fminf(fmaxf(tvl_in[0], 0.f), 1.f);

    if (tid < NBATCH) {
        float vv[NFEAT], lwp[NFEAT];
        float mp = -1e30f, mm = -1e30f;
#pragma unroll
        for (int ff = 0; ff < NFEAT; ++ff) {
            const float pc = fminf(fmaxf(p[ff], 0.f), 1.f);
            const float lwf = __logf(pc + EPSW);
            const float v = r1[tid * NFEAT + ff];
            vv[ff] = v; lwp[ff] = lwf;
            mp = fmaxf(mp, fmaf(BETA, v, lwf));
            mm = fmaxf(mm, fmaf(-BETA, v, lwf));
        }
        float sp = 0.f, np = 0.f, sm = 0.f, nm = 0.f;
#pragma unroll
        for (int ff = 0; ff < NFEAT; ++ff) {
            const float ep = __expf(fmaf(BETA, vv[ff], lwp[ff]) - mp);
            sp += ep; np = fmaf(ep, vv[ff], np);
            const float em = __expf(fmaf(-BETA, vv[ff], lwp[ff]) - mm);
            sm += em; nm = fmaf(em, vv[ff], nm);
        }
        out[tid] = tvl * (np / sp) + (1.f - tvl) * (nm / sm);
    }

    if (tid == 0) {
        float bi = 0.f, l2 = 0.f;
#pragma unroll
        for (int k = 0; k < 2 * NFEAT; ++k) {
            const float t = fminf(fmaxf(tvt[k], 0.f), 1.f);
            bi += t * (1.f - t);
        }
        bi += tvl * (1.f - tvl);
#pragma unroll
        for (int ff = 0; ff < NFEAT; ++ff) {
            const float pc = fminf(fmaxf(p[ff], 0.f), 1.f);
            bi += pc * (1.f - pc);
            l2 = fmaf(pc, pc, l2);
        }
        out[NBATCH] = W_BI * bi + W_L2 * l2;
    }
}

extern "C" void kernel_launch(void* const* d_in, const int* in_sizes, int n_in,
                              void* d_out, int out_size, void* d_ws, size_t ws_size,
                              hipStream_t stream)
{
    const float* x   = (const float*)d_in[0];
    const float* t1  = (const float*)d_in[1];
    const float* t2  = (const float*)d_in[2];
    const float* a   = (const float*)d_in[3];
    const float* b   = (const float*)d_in[4];
    const float* p   = (const float*)d_in[5];
    const float* tvt = (const float*)d_in[6];
    const float* tvl = (const float*)d_in[7];
    float* out = (float*)d_out;
    float* r1  = (float*)d_ws;   // NBATCH*NFEAT floats scratch

    stage12_kernel<<<NBATCH * NFEAT, 256, 0, stream>>>(x, t1, t2, a, b, tvt, r1);
    stage3_kernel<<<1, 64, 0, stream>>>(r1, p, tvt, tvl, out);
}

// Round 4
// 13.650 us; speedup vs baseline: 1.8575x; 1.2157x over previous
//
#include <hip/hip_runtime.h>
#include <math.h>

#define TLEN   256
#define NFEAT  16
#define NBATCH 32
#define BETA   2.5f
#define EPSW   1e-12f
#define W_BI   0.05f
#define W_L2   0.01f
#define L2E    1.4426950408889634f
#define LB     (BETA * L2E)

#if __has_builtin(__builtin_amdgcn_exp2f)
#define EXP2(x) __builtin_amdgcn_exp2f(x)
#else
#define EXP2(x) exp2f(x)
#endif

__device__ inline float sigm(float v) { return 1.f / (1.f + __expf(-v)); }

__device__ inline float wredmax(float v) {
#pragma unroll
    for (int o = 32; o; o >>= 1) v = fmaxf(v, __shfl_xor(v, o));
    return v;
}
__device__ inline float wredmin(float v) {
#pragma unroll
    for (int o = 32; o; o >>= 1) v = fminf(v, __shfl_xor(v, o));
    return v;
}
__device__ inline float wredsum(float v) {
#pragma unroll
    for (int o = 32; o; o >>= 1) v += __shfl_xor(v, o);
    return v;
}

// One block per (batch, feature): 256 threads; thread index serves as t / j / i.
__global__ __launch_bounds__(256) void stage12_kernel(
    const float* __restrict__ x, const float* __restrict__ t1,
    const float* __restrict__ t2, const float* __restrict__ a,
    const float* __restrict__ b, const float* __restrict__ tvt,
    float* __restrict__ r1_out)
{
    const int bf   = blockIdx.x;
    const int bb   = bf >> 4;
    const int f    = bf & 15;
    const int tid  = threadIdx.x;
    const int wave = tid >> 6;
    const int lane = tid & 63;

    __shared__ float4 PQ[256];     // (E, E*blv, Em, Em*blv)
    __shared__ float4 PS[257];     // exclusive prefix sums of PQ
    __shared__ float  wpe[256];    // w1 + eps
    __shared__ float4 wt4[4];
    __shared__ float  redA[4], redB[4], redC[4], redD[4];

    // ---- window-1 params (uniform across block) ----
    float t2h = fminf(fmaxf(t2[f], 0.f), (float)(TLEN - 1));
    float t1h = fminf(fmaxf(t1[f], 0.f), (float)(TLEN - 1));
    t1h = (t1h >= t2h - 1.f) ? (t2h - 1.f) : t1h;

    // ---- signal value for this t = tid ----
    const float v   = a[f] * x[(bb * TLEN + tid) * 2] - b[f];
    const float blv = LB * v;

    {
        const float wm = wredmax(v), wn = wredmin(v);
        if (lane == 0) { redA[wave] = wm; redB[wave] = wn; }
    }

    // ---- w1 + eps for j = tid ----
    const float jj = (float)tid;
    const float w1 = sigm(BETA * (jj - t1h)) * sigm(BETA * (t2h - jj));
    wpe[tid] = w1 + EPSW;
    __syncthreads();  // S1: redA/redB + wpe ready

    const float vmax = fmaxf(fmaxf(redA[0], redA[1]), fmaxf(redA[2], redA[3]));
    const float vmin = fminf(fminf(redB[0], redB[1]), fminf(redB[2], redB[3]));

    // exponentials (global shift => E, Em in (0,1])
    const float Ep = EXP2(blv - LB * vmax);
    const float Em = EXP2(LB * vmin - blv);
    const float4 q = make_float4(Ep, Ep * blv, Em, Em * blv);
    PQ[tid] = q;

    // wave-level inclusive scan of q
    float4 sc = q;
#pragma unroll
    for (int off = 1; off < 64; off <<= 1) {
        const float ox = __shfl_up(sc.x, off), oy = __shfl_up(sc.y, off);
        const float oz = __shfl_up(sc.z, off), ow = __shfl_up(sc.w, off);
        if (lane >= off) { sc.x += ox; sc.y += oy; sc.z += oz; sc.w += ow; }
    }
    if (lane == 63) wt4[wave] = sc;
    __syncthreads();  // S2: PQ + wave totals ready

    {
        float ax = 0.f, ay = 0.f, az = 0.f, aw = 0.f;
        for (int w = 0; w < wave; ++w) {
            const float4 t = wt4[w];
            ax += t.x; ay += t.y; az += t.z; aw += t.w;
        }
        PS[tid + 1] = make_float4(sc.x + ax, sc.y + ay, sc.z + az, sc.w + aw);
        if (tid == 0) PS[0] = make_float4(0.f, 0.f, 0.f, 0.f);
    }
    __syncthreads();  // S3: PS ready

    // ---- stage 1 bounds (block-uniform) ----
    const int it1  = (int)t1h, it2 = (int)t2h;
    const int jbeg = max(0, it1 - 16);
    const int jc0  = it1 + 7;                       // first core j (w==1 side)
    int       jc1  = (int)(t2h - 6.f);              // last core j
    if (jc1 < jc0) jc1 = jc0 - 1;                   // empty core degenerates safely
    const int jend = min(TLEN - 1, it2 + 17);

    const int i = tid;
    const float4 PQ255 = PQ[255];

    // core via prefix difference + exact clamp count
    float sp, np, sm, nm;
    {
        const int lo = i + jc0, hi = i + jc1;
        const float4 psh = PS[min(hi + 1, 256)];
        const float4 psl = PS[min(lo, 256)];
        const float cf = (float)(max(0, hi - 255) - max(0, lo - 256));
        sp = psh.x - psl.x + cf * PQ255.x;
        np = psh.y - psl.y + cf * PQ255.y;
        sm = psh.z - psl.z + cf * PQ255.z;
        nm = psh.w - psl.w + cf * PQ255.w;
    }

    // edge regions (direct, exact weights, clamp via min)
#pragma unroll 4
    for (int j = jbeg; j < jc0; ++j) {
        const float  wj = wpe[j];
        const float4 pq = PQ[min(i + j, 255)];
        sp = fmaf(wj, pq.x, sp); np = fmaf(wj, pq.y, np);
        sm = fmaf(wj, pq.z, sm); nm = fmaf(wj, pq.w, nm);
    }
#pragma unroll 4
    for (int j = jc1 + 1; j <= jend; ++j) {
        const float  wj = wpe[j];
        const float4 pq = PQ[min(i + j, 255)];
        sp = fmaf(wj, pq.x, sp); np = fmaf(wj, pq.y, np);
        sm = fmaf(wj, pq.z, sm); nm = fmaf(wj, pq.w, nm);
    }

    const float F1  = np / sp;            // in blv units
    const float G1  = nm / sm;
    const float tv0 = fminf(fmaxf(tvt[f], 0.f), 1.f);
    const float y   = (tv0 * F1 + (1.f - tv0) * G1) * (1.f / LB);  // back to v units

    // ---- stage-2 weights for i = tid ----
    float lw2;
    {
        float t2h2 = fminf(fmaxf(t2[NFEAT + f], 0.f), (float)(TLEN - 1));
        float t1h2 = fminf(fmaxf(t1[NFEAT + f], 0.f), (float)(TLEN - 1));
        t1h2 = (t1h2 >= t2h2 - 1.f) ? (t2h2 - 1.f) : t1h2;
        const float w2 = sigm(BETA * (jj - t1h2)) * sigm(BETA * (t2h2 - jj));
        lw2 = __logf(w2 + EPSW);
    }

    // ---- stage 2: weighted soft max/min over i ----
    {
        const float ym = wredmax(y), yn = wredmin(y);
        if (lane == 0) { redA[wave] = ym; redB[wave] = yn; }
    }
    __syncthreads();  // S4
    const float ymax = fmaxf(fmaxf(redA[0], redA[1]), fmaxf(redA[2], redA[3]));
    const float ymin = fminf(fminf(redB[0], redB[1]), fminf(redB[2], redB[3]));

    const float ep2 = EXP2(fmaf(LB, y - ymax, L2E * lw2));
    const float em2 = EXP2(fmaf(LB, ymin - y, L2E * lw2));
    float c0 = wredsum(ep2);
    float c1 = wredsum(ep2 * y);
    float c2 = wredsum(em2);
    float c3 = wredsum(em2 * y);
    __syncthreads();  // S5 (everyone done reading redA/redB)
    if (lane == 0) { redA[wave] = c0; redB[wave] = c1; redC[wave] = c2; redD[wave] = c3; }
    __syncthreads();  // S6
    if (tid == 0) {
        const float SP2 = redA[0] + redA[1] + redA[2] + redA[3];
        const float NP2 = redB[0] + redB[1] + redB[2] + redB[3];
        const float SM2 = redC[0] + redC[1] + redC[2] + redC[3];
        const float NM2 = redD[0] + redD[1] + redD[2] + redD[3];
        const float F2 = NP2 / SP2, G2 = NM2 / SM2;
        const float tv1 = fminf(fmaxf(tvt[NFEAT + f], 0.f), 1.f);
        r1_out[bb * NFEAT + f] = tv1 * F2 + (1.f - tv1) * G2;
    }
}

// One small block: stage-3 logical soft max/min over features + penalty scalar.
__global__ __launch_bounds__(64) void stage3_kernel(
    const float* __restrict__ r1, const float* __restrict__ p,
    const float* __restrict__ tvt, const float* __restrict__ tvl_in,
    float* __restrict__ out)
{
    const int tid = threadIdx.x;
    const float tvl = fminf(fmaxf(tvl_in[0], 0.f), 1.f);

    if (tid < NBATCH) {
        float vv[NFEAT], lwp[NFEAT];
        float mp = -1e30f, mm = -1e30f;
#pragma unroll
        for (int ff = 0; ff < NFEAT; ++ff) {
            const float pc = fminf(fmaxf(p[ff], 0.f), 1.f);
            const float lwf = __logf(pc + EPSW);
            const float v = r1[tid * NFEAT + ff];
            vv[ff] = v; lwp[ff] = lwf;
            mp = fmaxf(mp, fmaf(BETA, v, lwf));
            mm = fmaxf(mm, fmaf(-BETA, v, lwf));
        }
        float sp = 0.f, np = 0.f, sm = 0.f, nm = 0.f;
#pragma unroll
        for (int ff = 0; ff < NFEAT; ++ff) {
            const float ep = __expf(fmaf(BETA, vv[ff], lwp[ff]) - mp);
            sp += ep; np = fmaf(ep, vv[ff], np);
            const float em = __expf(fmaf(-BETA, vv[ff], lwp[ff]) - mm);
            sm += em; nm = fmaf(em, vv[ff], nm);
        }
        out[tid] = tvl * (np / sp) + (1.f - tvl) * (nm / sm);
    }

    if (tid == 0) {
        float bi = 0.f, l2 = 0.f;
#pragma unroll
        for (int k = 0; k < 2 * NFEAT; ++k) {
            const float t = fminf(fmaxf(tvt[k], 0.f), 1.f);
            bi += t * (1.f - t);
        }
        bi += tvl * (1.f - tvl);
#pragma unroll
        for (int ff = 0; ff < NFEAT; ++ff) {
            const float pc = fminf(fmaxf(p[ff], 0.f), 1.f);
            bi += pc * (1.f - pc);
            l2 = fmaf(pc, pc, l2);
        }
        out[NBATCH] = W_BI * bi + W_L2 * l2;
    }
}

extern "C" void kernel_launch(void* const* d_in, const int* in_sizes, int n_in,
                              void* d_out, int out_size, void* d_ws, size_t ws_size,
                              hipStream_t stream)
{
    const float* x   = (const float*)d_in[0];
    const float* t1  = (const float*)d_in[1];
    const float* t2  = (const float*)d_in[2];
    const float* a   = (const float*)d_in[3];
    const float* b   = (const float*)d_in[4];
    const float* p   = (const float*)d_in[5];
    const float* tvt = (const float*)d_in[6];
    const float* tvl = (const float*)d_in[7];
    float* out = (float*)d_out;
    float* r1  = (float*)d_ws;   // NBATCH*NFEAT floats scratch

    stage12_kernel<<<NBATCH * NFEAT, 256, 0, stream>>>(x, t1, t2, a, b, tvt, r1);
    stage3_kernel<<<1, 64, 0, stream>>>(r1, p, tvt, tvl, out);
}